// Round 10
// baseline (164.315 us; speedup 1.0000x reference)
//
#include <hip/hip_runtime.h>
#include <hip/hip_bf16.h>

#define NL 4096   // 64*64 low-res pixels
#define HH 32
#define WH 32

typedef __attribute__((ext_vector_type(8))) short s8v;   // 8 bf16 MFMA A/B frag
typedef __attribute__((ext_vector_type(4))) short s4v;   // 4 bf16 (8B)
typedef __attribute__((ext_vector_type(4))) float f32x4; // MFMA C/D frag

static __device__ inline unsigned short f2bf(float x) {
  __hip_bfloat16 h = __float2bfloat16(x);   // RNE
  return *reinterpret_cast<unsigned short*>(&h);
}
static __device__ inline float bfbits2f(unsigned int lo16) {
  unsigned int u = lo16 << 16;
  return *reinterpret_cast<float*>(&u);
}
// load 8 consecutive fp32 and convert to a bf16 MFMA fragment
static __device__ inline s8v ldcvt8(const float* __restrict__ p) {
  float4 u = *(const float4*)p;
  float4 v = *(const float4*)(p + 4);
  s8v r;
  r[0] = (short)f2bf(u.x); r[1] = (short)f2bf(u.y);
  r[2] = (short)f2bf(u.z); r[3] = (short)f2bf(u.w);
  r[4] = (short)f2bf(v.x); r[5] = (short)f2bf(v.y);
  r[6] = (short)f2bf(v.z); r[7] = (short)f2bf(v.w);
  return r;
}

// ---------------------------------------------------------------------------
// K1: fused prep + stageA + stageB (round-8 structure, fp32 weights inline).
// 512 blocks x 256 thr (4 waves); 16 pixels/block.
// Also converts Wb -> bf16 (192 elems/block) for K2.
// ---------------------------------------------------------------------------
__global__ __launch_bounds__(256) void k1_fused(
    const float* __restrict__ low, const float* __restrict__ high,
    const float* __restrict__ W1, const float* __restrict__ b1,
    const float* __restrict__ W2, const float* __restrict__ b2,
    const float* __restrict__ Wq, const float* __restrict__ bq,
    const float* __restrict__ Wk, const float* __restrict__ bk,
    const float* __restrict__ Wv, const float* __restrict__ bv,
    const float* __restrict__ Woff, const float* __restrict__ boff,
    const float* __restrict__ Wb, short* __restrict__ wbc,
    short* __restrict__ xh, float* __restrict__ q_t, float* __restrict__ k_t,
    float* __restrict__ off_t, short* __restrict__ v_t) {
  __shared__ short xin_s[16 * 520];
  __shared__ short qf_s[16 * 136];
  __shared__ short vf_s[16 * 136];
  const int tid = threadIdx.x;
  const int pix0 = blockIdx.x * 16;
  const int b = pix0 >> 12;
  const int n0 = pix0 & (NL - 1);

  // ---- side task: convert this block's slice of Wb (192 elems) ----
  {
    int i = blockIdx.x * 192 + tid;
    if (tid < 192) wbc[i] = (short)f2bf(Wb[i]);
  }

  // ---- phase P: build xin tile ----
  {
    const int nl = tid & 15, cg = tid >> 4;
    const int n = n0 + nl;
    const int y = n >> 6, x = n & 63;
    float sx = x * 0.5f - 0.25f;
    float sy = y * 0.5f - 0.25f;
    float x0f = floorf(sx), y0f = floorf(sy);
    float wx = sx - x0f, wy = sy - y0f;
    int x0i = (int)x0f, y0i = (int)y0f;
    int x0c = min(WH - 1, max(0, x0i)), x1c = min(WH - 1, max(0, x0i + 1));
    int y0c = min(HH - 1, max(0, y0i)), y1c = min(HH - 1, max(0, y0i + 1));
    float w00 = (1.f - wy) * (1.f - wx), w01 = (1.f - wy) * wx;
    float w10 = wy * (1.f - wx),         w11 = wy * wx;
#pragma unroll
    for (int i = 0; i < 16; i++) {
      int c = cg * 16 + i;
      const float* f = high + (size_t)(b * 256 + c) * (HH * WH);
      float v = w00 * f[y0c * WH + x0c] + w01 * f[y0c * WH + x1c]
              + w10 * f[y1c * WH + x0c] + w11 * f[y1c * WH + x1c];
      xin_s[nl * 520 + c] = (short)f2bf(v);
      xin_s[nl * 520 + 256 + c] =
          (short)f2bf(low[(size_t)(b * 256 + c) * NL + n]);
    }
  }
  __syncthreads();

  // ---- store xh (high half of xin, needed by K2 final GEMM) ----
  {
    const int r = tid >> 4, c0 = (tid & 15) * 16;
    s8v v0 = *(const s8v*)(xin_s + r * 520 + c0);
    s8v v1 = *(const s8v*)(xin_s + r * 520 + c0 + 8);
    *(s8v*)(xh + (size_t)(pix0 + r) * 256 + c0) = v0;
    *(s8v*)(xh + (size_t)(pix0 + r) * 256 + c0 + 8) = v1;
  }

  const int wave = tid >> 6, lane = tid & 63;
  const int quad = lane >> 4, id = lane & 15;

  // ---- phase A1: qf = W1 @ xin, M=128 K=512 (2 frags/wave) ----
  {
    f32x4 acc0 = (f32x4){0.f, 0.f, 0.f, 0.f};
    f32x4 acc1 = (f32x4){0.f, 0.f, 0.f, 0.f};
    const float* a0 = W1 + (size_t)(wave * 32 + id) * 512 + quad * 8;
    const float* a1 = a0 + 16 * 512;
    const short* bp = xin_s + id * 520 + quad * 8;
#pragma unroll
    for (int kk = 0; kk < 512; kk += 32) {
      s8v bf = *(const s8v*)(bp + kk);
      acc0 = __builtin_amdgcn_mfma_f32_16x16x32_bf16(ldcvt8(a0 + kk), bf, acc0, 0, 0, 0);
      acc1 = __builtin_amdgcn_mfma_f32_16x16x32_bf16(ldcvt8(a1 + kk), bf, acc1, 0, 0, 0);
    }
    int m0 = wave * 32 + quad * 4;
    s4v o0, o1;
#pragma unroll
    for (int r = 0; r < 4; r++) {
      o0[r] = (short)f2bf(acc0[r] + b1[m0 + r]);
      o1[r] = (short)f2bf(acc1[r] + b1[m0 + 16 + r]);
    }
    *(s4v*)(qf_s + id * 136 + m0) = o0;
    *(s4v*)(qf_s + id * 136 + m0 + 16) = o1;
  }

  // ---- phase A2: vf = W2 @ xin[:,0:256], M=128 K=256 ----
  {
    f32x4 acc0 = (f32x4){0.f, 0.f, 0.f, 0.f};
    f32x4 acc1 = (f32x4){0.f, 0.f, 0.f, 0.f};
    const float* a0 = W2 + (size_t)(wave * 32 + id) * 256 + quad * 8;
    const float* a1 = a0 + 16 * 256;
    const short* bp = xin_s + id * 520 + quad * 8;
#pragma unroll
    for (int kk = 0; kk < 256; kk += 32) {
      s8v bf = *(const s8v*)(bp + kk);
      acc0 = __builtin_amdgcn_mfma_f32_16x16x32_bf16(ldcvt8(a0 + kk), bf, acc0, 0, 0, 0);
      acc1 = __builtin_amdgcn_mfma_f32_16x16x32_bf16(ldcvt8(a1 + kk), bf, acc1, 0, 0, 0);
    }
    int m0 = wave * 32 + quad * 4;
    s4v o0, o1;
#pragma unroll
    for (int r = 0; r < 4; r++) {
      o0[r] = (short)f2bf(acc0[r] + b2[m0 + r]);
      o1[r] = (short)f2bf(acc1[r] + b2[m0 + 16 + r]);
    }
    *(s4v*)(vf_s + id * 136 + m0) = o0;
    *(s4v*)(vf_s + id * 136 + m0 + 16) = o1;
  }
  __syncthreads();

  // ---- phase B: 14 m-frags (0:q, 1-4:off, 5:k, 6-13:v), K=128 ----
  for (int f = wave; f < 14; f += 4) {
    const float* ap;
    if      (f == 0) ap = Wq   + (size_t)id * 128;
    else if (f <  5) ap = Woff + (size_t)((f - 1) * 16 + id) * 128;
    else if (f == 5) ap = Wk   + (size_t)id * 128;
    else             ap = Wv   + (size_t)((f - 6) * 16 + id) * 128;
    ap += quad * 8;
    const short* bp = (f < 5 ? qf_s : vf_s) + id * 136 + quad * 8;
    f32x4 acc = (f32x4){0.f, 0.f, 0.f, 0.f};
#pragma unroll
    for (int kk = 0; kk < 128; kk += 32)
      acc = __builtin_amdgcn_mfma_f32_16x16x32_bf16(
          ldcvt8(ap + kk), *(const s8v*)(bp + kk), acc, 0, 0, 0);
    const int pix = pix0 + id;
    const int mq = quad * 4;
    if (f == 0) {
      f32x4 v;
#pragma unroll
      for (int r = 0; r < 4; r++) v[r] = acc[r] + bq[mq + r];
      *(f32x4*)(q_t + (size_t)pix * 16 + mq) = v;
    } else if (f < 5) {
      int m = (f - 1) * 16 + mq;
      f32x4 v;
#pragma unroll
      for (int r = 0; r < 4; r++) v[r] = acc[r] + boff[m + r];
      *(f32x4*)(off_t + (size_t)pix * 64 + m) = v;
    } else if (f == 5) {
      f32x4 v;
#pragma unroll
      for (int r = 0; r < 4; r++) v[r] = acc[r] + bk[mq + r];
      *(f32x4*)(k_t + (size_t)pix * 16 + mq) = v;
    } else {
      int m = (f - 6) * 16 + mq;
      s4v o;
#pragma unroll
      for (int r = 0; r < 4; r++) o[r] = (short)f2bf(acc[r] + bv[m + r]);
      *(s4v*)(v_t + (size_t)pix * 128 + m) = o;
    }
  }
}

// ---------------------------------------------------------------------------
// K2: fused deformable attention + final GEMM (+BN+ReLU). Unchanged (round 8).
// 512 blocks x 1024 thr; wave w owns query pix0+w; tap-parallel V-gather.
// ---------------------------------------------------------------------------
__global__ __launch_bounds__(1024, 2) void k2_fused(
    const float* __restrict__ q_t, const float* __restrict__ k_t,
    const short* __restrict__ v_t, const float* __restrict__ off_t,
    const short* __restrict__ xh, const short* __restrict__ wb,
    const float* __restrict__ gamma, const float* __restrict__ beta,
    const float* __restrict__ rmean, const float* __restrict__ rvar,
    float* __restrict__ out) {
  __shared__ float s_w[16][32][4];   // 8 KB
  __shared__ int   s_i[16][32][4];   // 8 KB
  __shared__ short attn_s[16 * 136]; // 4.25 KB
  const int tid = threadIdx.x;
  const int wave = tid >> 6, lane = tid & 63;
  const int pix0 = blockIdx.x * 16;

  // ---- phase T: attention, ONE query per wave ----
  {
    const int qidx = pix0 + wave;
    const int b = qidx >> 12;
    const int n = qidx & (NL - 1);
    const int qy = n >> 6, qx = n & 63;

    const float* qp = q_t + (size_t)qidx * 16;
    float qreg[16];
#pragma unroll
    for (int i = 0; i < 16; i += 4) {
      float4 t = *(const float4*)(qp + i);
      qreg[i] = t.x; qreg[i + 1] = t.y; qreg[i + 2] = t.z; qreg[i + 3] = t.w;
    }

    const int pt = lane >> 1, h = lane & 1;
    float2 dxy = *(const float2*)(off_t + (size_t)qidx * 64 + 2 * pt);
    float sx = (float)qx + dxy.x;
    float sy = (float)qy + dxy.y;
    float x0f = floorf(sx), y0f = floorf(sy);
    float wx = sx - x0f, wy = sy - y0f;
    int x0i = (int)x0f, y0i = (int)y0f;
    int x0 = min(63, max(0, x0i)), x1 = min(63, max(0, x0i + 1));
    int y0 = min(63, max(0, y0i)), y1 = min(63, max(0, y0i + 1));

    int   yr  = h ? y1 : y0;
    float wyr = h ? wy : (1.f - wy);
    int   pa = yr * 64 + x0, pb = yr * 64 + x1;
    float wa = wyr * (1.f - wx), wb_ = wyr * wx;

    const float* kb = k_t + (size_t)b * NL * 16;
    float da = 0.f, db = 0.f;
    {
      const float* ka = kb + (size_t)pa * 16;
      const float* kc = kb + (size_t)pb * 16;
#pragma unroll
      for (int i = 0; i < 16; i += 4) {
        float4 a4 = *(const float4*)(ka + i);
        float4 c4 = *(const float4*)(kc + i);
        da = fmaf(qreg[i], a4.x, da); da = fmaf(qreg[i + 1], a4.y, da);
        da = fmaf(qreg[i + 2], a4.z, da); da = fmaf(qreg[i + 3], a4.w, da);
        db = fmaf(qreg[i], c4.x, db); db = fmaf(qreg[i + 1], c4.y, db);
        db = fmaf(qreg[i + 2], c4.z, db); db = fmaf(qreg[i + 3], c4.w, db);
      }
    }
    float part = wa * da + wb_ * db;
    part += __shfl_xor(part, 1, 64);
    float logit = part * 0.25f;

    float m = logit;
#pragma unroll
    for (int s = 32; s > 0; s >>= 1) m = fmaxf(m, __shfl_xor(m, s, 64));
    float e = __expf(logit - m);
    float ssum = e;
#pragma unroll
    for (int s = 32; s > 0; s >>= 1) ssum += __shfl_xor(ssum, s, 64);
    float a = e * 2.f / ssum;   // ssum double-counts each point

    // per-wave tables; same-wave LDS RAW is lgkmcnt-ordered -> no barrier
    s_w[wave][pt][2 * h + 0] = a * wa;
    s_w[wave][pt][2 * h + 1] = a * wb_;
    s_i[wave][pt][2 * h + 0] = pa;
    s_i[wave][pt][2 * h + 1] = pb;

    // ---- V-gather: tap-parallel, 8 channels per lane per point ----
    const int t = lane >> 4, chunk = lane & 15;
    const short* vb = v_t + (size_t)b * NL * 128 + chunk * 8;
    float o[8];
#pragma unroll
    for (int j = 0; j < 8; j++) o[j] = 0.f;
#pragma unroll
    for (int pp = 0; pp < 32; pp++) {
      float w_ = s_w[wave][pp][t];
      int  pix = s_i[wave][pp][t];
      uint4 u = *(const uint4*)(vb + (size_t)pix * 128);
      o[0] = fmaf(w_, bfbits2f(u.x & 0xffffu), o[0]);
      o[1] = fmaf(w_, bfbits2f(u.x >> 16),     o[1]);
      o[2] = fmaf(w_, bfbits2f(u.y & 0xffffu), o[2]);
      o[3] = fmaf(w_, bfbits2f(u.y >> 16),     o[3]);
      o[4] = fmaf(w_, bfbits2f(u.z & 0xffffu), o[4]);
      o[5] = fmaf(w_, bfbits2f(u.z >> 16),     o[5]);
      o[6] = fmaf(w_, bfbits2f(u.w & 0xffffu), o[6]);
      o[7] = fmaf(w_, bfbits2f(u.w >> 16),     o[7]);
    }
    // reduce across the 4 tap-groups (lane bits 4,5)
#pragma unroll
    for (int j = 0; j < 8; j++) {
      o[j] += __shfl_xor(o[j], 16, 64);
      o[j] += __shfl_xor(o[j], 32, 64);
    }
    if (t == 0) {
      uint4 pk;
      pk.x = (unsigned)f2bf(o[0]) | ((unsigned)f2bf(o[1]) << 16);
      pk.y = (unsigned)f2bf(o[2]) | ((unsigned)f2bf(o[3]) << 16);
      pk.z = (unsigned)f2bf(o[4]) | ((unsigned)f2bf(o[5]) << 16);
      pk.w = (unsigned)f2bf(o[6]) | ((unsigned)f2bf(o[7]) << 16);
      *(uint4*)(attn_s + wave * 136 + chunk * 8) = pk;
    }
  }
  __syncthreads();

  // ---- phase F: final GEMM, N=16 px, M=256 over 16 waves (1 frag/wave) ----
  {
    const int quad = lane >> 4, id = lane & 15;
    const int m0 = wave * 16;
    const int pix = pix0 + id;

    f32x4 acc = (f32x4){0.f, 0.f, 0.f, 0.f};
    const short* ap = wb + (size_t)(m0 + id) * 384 + quad * 8;
    const short* bs = attn_s + id * 136 + quad * 8;
    const short* bg = xh + (size_t)pix * 256 + quad * 8;
#pragma unroll
    for (int k = 0; k < 4; k++)
      acc = __builtin_amdgcn_mfma_f32_16x16x32_bf16(
          *(const s8v*)(ap + k * 32), *(const s8v*)(bs + k * 32), acc, 0, 0, 0);
#pragma unroll
    for (int k = 0; k < 8; k++)
      acc = __builtin_amdgcn_mfma_f32_16x16x32_bf16(
          *(const s8v*)(ap + 128 + k * 32), *(const s8v*)(bg + k * 32), acc, 0, 0, 0);

    const int bb = pix >> 12, nlow = pix & (NL - 1);
    const int mbase = m0 + quad * 4;
#pragma unroll
    for (int r = 0; r < 4; r++) {
      int o = mbase + r;
      float s  = gamma[o] * rsqrtf(rvar[o] + 1e-5f);
      float sh = beta[o] - rmean[o] * s;
      out[((size_t)bb * 256 + o) * NL + nlow] = fmaxf(fmaf(acc[r], s, sh), 0.f);
    }
  }
}

// ---------------------------------------------------------------------------
extern "C" void kernel_launch(void* const* d_in, const int* in_sizes, int n_in,
                              void* d_out, int out_size, void* d_ws, size_t ws_size,
                              hipStream_t stream) {
  const float* low   = (const float*)d_in[0];
  const float* high  = (const float*)d_in[1];
  const float* W1    = (const float*)d_in[2];
  const float* b1    = (const float*)d_in[3];
  const float* W2    = (const float*)d_in[4];
  const float* b2    = (const float*)d_in[5];
  const float* Wq    = (const float*)d_in[6];
  const float* bq    = (const float*)d_in[7];
  const float* Wk    = (const float*)d_in[8];
  const float* bk    = (const float*)d_in[9];
  const float* Wv    = (const float*)d_in[10];
  const float* bv    = (const float*)d_in[11];
  const float* Woff  = (const float*)d_in[12];
  const float* boff  = (const float*)d_in[13];
  const float* Wb    = (const float*)d_in[14];
  const float* gamma = (const float*)d_in[15];
  const float* beta  = (const float*)d_in[16];
  const float* rmean = (const float*)d_in[17];
  const float* rvar  = (const float*)d_in[18];
  float* out = (float*)d_out;

  short* ws    = (short*)d_ws;
  short* xh    = ws;                    // [8192][256] bf16 = 2,097,152 sh
  short* v_t   = xh + 2097152;          // [8192][128] bf16
  short* wbc   = v_t + 1048576;         // Wb bf16 [256][384] = 98,304 sh
  float* q_t   = (float*)(wbc + 98304); // [8192][16] f32
  float* k_t   = q_t + 131072;          // [8192][16] f32
  float* off_t = k_t + 131072;          // [8192][64] f32

  k1_fused<<<512, 256, 0, stream>>>(low, high, W1, b1, W2, b2, Wq, bq, Wk, bk,
                                    Wv, bv, Woff, boff, Wb, wbc,
                                    xh, q_t, k_t, off_t, v_t);
  k2_fused<<<512, 1024, 0, stream>>>(q_t, k_t, v_t, off_t, xh, wbc,
                                     gamma, beta, rmean, rvar, out);
}

// Round 11
// 157.347 us; speedup vs baseline: 1.0443x; 1.0443x over previous
//
#include <hip/hip_runtime.h>
#include <hip/hip_bf16.h>

#define NL 4096   // 64*64 low-res pixels
#define HH 32
#define WH 32

typedef __attribute__((ext_vector_type(8))) short s8v;   // 8 bf16 MFMA A/B frag
typedef __attribute__((ext_vector_type(4))) short s4v;   // 4 bf16 (8B)
typedef __attribute__((ext_vector_type(4))) float f32x4; // MFMA C/D frag

static __device__ inline unsigned short f2bf(float x) {
  __hip_bfloat16 h = __float2bfloat16(x);   // RNE
  return *reinterpret_cast<unsigned short*>(&h);
}
static __device__ inline float bfbits2f(unsigned int lo16) {
  unsigned int u = lo16 << 16;
  return *reinterpret_cast<float*>(&u);
}

// ---------------------------------------------------------------------------
// Weight fp32 -> bf16, packed:
//   [0,65536)        W1   [128][512]
//   [65536,98304)    W2   [128][256]
//   [98304,100352)   Wq   [16][128]   \
//   [100352,108544)  Woff [64][128]    | stage-B concat: 224 rows, K=128
//   [108544,110592)  Wk   [16][128]    |
//   [110592,126976)  Wv   [128][128]  /
//   [126976,225280)  Wb   [256][384]
// ---------------------------------------------------------------------------
__global__ __launch_bounds__(256) void convert_weights_k(
    const float* __restrict__ w1, const float* __restrict__ w2,
    const float* __restrict__ wq, const float* __restrict__ woff,
    const float* __restrict__ wk, const float* __restrict__ wv,
    const float* __restrict__ wb, short* __restrict__ dst) {
  int i = blockIdx.x * 256 + threadIdx.x;
  const float* src; int off;
  if      (i <  65536) { src = w1;   off = 0; }
  else if (i <  98304) { src = w2;   off = 65536; }
  else if (i < 100352) { src = wq;   off = 98304; }
  else if (i < 108544) { src = woff; off = 100352; }
  else if (i < 110592) { src = wk;   off = 108544; }
  else if (i < 126976) { src = wv;   off = 110592; }
  else if (i < 225280) { src = wb;   off = 126976; }
  else return;
  dst[i] = (short)f2bf(src[i - off]);
}

// ---------------------------------------------------------------------------
// K1: fused prep + stageA + stageB (round-8 structure; phase A interleaved:
// first 256 of K runs A1+A2 as 4 concurrent MFMA chains sharing B-frag reads).
// 512 blocks x 256 thr; 16 pixels/block.
// ---------------------------------------------------------------------------
__global__ __launch_bounds__(256) void k1_fused(
    const float* __restrict__ low, const float* __restrict__ high,
    const short* __restrict__ wc,
    const float* __restrict__ b1, const float* __restrict__ b2,
    const float* __restrict__ bq, const float* __restrict__ boff,
    const float* __restrict__ bk, const float* __restrict__ bv,
    short* __restrict__ xh, float* __restrict__ q_t, float* __restrict__ k_t,
    float* __restrict__ off_t, short* __restrict__ v_t) {
  __shared__ short xin_s[16 * 520];
  __shared__ short qf_s[16 * 136];
  __shared__ short vf_s[16 * 136];
  const int tid = threadIdx.x;
  const int pix0 = blockIdx.x * 16;
  const int b = pix0 >> 12;
  const int n0 = pix0 & (NL - 1);

  // ---- phase P: build xin tile ----
  {
    const int nl = tid & 15, cg = tid >> 4;
    const int n = n0 + nl;
    const int y = n >> 6, x = n & 63;
    float sx = x * 0.5f - 0.25f;
    float sy = y * 0.5f - 0.25f;
    float x0f = floorf(sx), y0f = floorf(sy);
    float wx = sx - x0f, wy = sy - y0f;
    int x0i = (int)x0f, y0i = (int)y0f;
    int x0c = min(WH - 1, max(0, x0i)), x1c = min(WH - 1, max(0, x0i + 1));
    int y0c = min(HH - 1, max(0, y0i)), y1c = min(HH - 1, max(0, y0i + 1));
    float w00 = (1.f - wy) * (1.f - wx), w01 = (1.f - wy) * wx;
    float w10 = wy * (1.f - wx),         w11 = wy * wx;
#pragma unroll
    for (int i = 0; i < 16; i++) {
      int c = cg * 16 + i;
      const float* f = high + (size_t)(b * 256 + c) * (HH * WH);
      float v = w00 * f[y0c * WH + x0c] + w01 * f[y0c * WH + x1c]
              + w10 * f[y1c * WH + x0c] + w11 * f[y1c * WH + x1c];
      xin_s[nl * 520 + c] = (short)f2bf(v);
      xin_s[nl * 520 + 256 + c] =
          (short)f2bf(low[(size_t)(b * 256 + c) * NL + n]);
    }
  }
  __syncthreads();

  // ---- store xh (high half of xin, needed by K2 final GEMM) ----
  {
    const int r = tid >> 4, c0 = (tid & 15) * 16;
    s8v v0 = *(const s8v*)(xin_s + r * 520 + c0);
    s8v v1 = *(const s8v*)(xin_s + r * 520 + c0 + 8);
    *(s8v*)(xh + (size_t)(pix0 + r) * 256 + c0) = v0;
    *(s8v*)(xh + (size_t)(pix0 + r) * 256 + c0 + 8) = v1;
  }

  const int wave = tid >> 6, lane = tid & 63;
  const int quad = lane >> 4, id = lane & 15;

  // ---- phase A (interleaved): qf = W1 @ xin (K=512), vf = W2 @ xin (K=256)
  //      4 concurrent MFMA chains over K<256 sharing one B-frag read/step ----
  {
    f32x4 acc0 = (f32x4){0.f, 0.f, 0.f, 0.f};   // A1 frag 0
    f32x4 acc1 = (f32x4){0.f, 0.f, 0.f, 0.f};   // A1 frag 1
    f32x4 acc2 = (f32x4){0.f, 0.f, 0.f, 0.f};   // A2 frag 0
    f32x4 acc3 = (f32x4){0.f, 0.f, 0.f, 0.f};   // A2 frag 1
    const short* a0 = wc + (size_t)(wave * 32 + id) * 512 + quad * 8;
    const short* a1 = a0 + 16 * 512;
    const short* a2 = wc + 65536 + (size_t)(wave * 32 + id) * 256 + quad * 8;
    const short* a3 = a2 + 16 * 256;
    const short* bp = xin_s + id * 520 + quad * 8;
#pragma unroll
    for (int kk = 0; kk < 256; kk += 32) {
      s8v bf = *(const s8v*)(bp + kk);
      acc0 = __builtin_amdgcn_mfma_f32_16x16x32_bf16(*(const s8v*)(a0 + kk), bf, acc0, 0, 0, 0);
      acc1 = __builtin_amdgcn_mfma_f32_16x16x32_bf16(*(const s8v*)(a1 + kk), bf, acc1, 0, 0, 0);
      acc2 = __builtin_amdgcn_mfma_f32_16x16x32_bf16(*(const s8v*)(a2 + kk), bf, acc2, 0, 0, 0);
      acc3 = __builtin_amdgcn_mfma_f32_16x16x32_bf16(*(const s8v*)(a3 + kk), bf, acc3, 0, 0, 0);
    }
#pragma unroll
    for (int kk = 256; kk < 512; kk += 32) {
      s8v bf = *(const s8v*)(bp + kk);
      acc0 = __builtin_amdgcn_mfma_f32_16x16x32_bf16(*(const s8v*)(a0 + kk), bf, acc0, 0, 0, 0);
      acc1 = __builtin_amdgcn_mfma_f32_16x16x32_bf16(*(const s8v*)(a1 + kk), bf, acc1, 0, 0, 0);
    }
    int m0 = wave * 32 + quad * 4;
    s4v o0, o1, o2, o3;
#pragma unroll
    for (int r = 0; r < 4; r++) {
      o0[r] = (short)f2bf(acc0[r] + b1[m0 + r]);
      o1[r] = (short)f2bf(acc1[r] + b1[m0 + 16 + r]);
      o2[r] = (short)f2bf(acc2[r] + b2[m0 + r]);
      o3[r] = (short)f2bf(acc3[r] + b2[m0 + 16 + r]);
    }
    *(s4v*)(qf_s + id * 136 + m0) = o0;
    *(s4v*)(qf_s + id * 136 + m0 + 16) = o1;
    *(s4v*)(vf_s + id * 136 + m0) = o2;
    *(s4v*)(vf_s + id * 136 + m0 + 16) = o3;
  }
  __syncthreads();

  // ---- phase B: 14 m-frags (0:q, 1-4:off, 5:k, 6-13:v), K=128 ----
  for (int f = wave; f < 14; f += 4) {
    const short* ap = wc + 98304 + (size_t)(f * 16 + id) * 128 + quad * 8;
    const short* bp = (f < 5 ? qf_s : vf_s) + id * 136 + quad * 8;
    f32x4 acc = (f32x4){0.f, 0.f, 0.f, 0.f};
#pragma unroll
    for (int kk = 0; kk < 128; kk += 32)
      acc = __builtin_amdgcn_mfma_f32_16x16x32_bf16(
          *(const s8v*)(ap + kk), *(const s8v*)(bp + kk), acc, 0, 0, 0);
    const int pix = pix0 + id;
    const int mq = quad * 4;
    if (f == 0) {
      f32x4 v;
#pragma unroll
      for (int r = 0; r < 4; r++) v[r] = acc[r] + bq[mq + r];
      *(f32x4*)(q_t + (size_t)pix * 16 + mq) = v;
    } else if (f < 5) {
      int m = (f - 1) * 16 + mq;
      f32x4 v;
#pragma unroll
      for (int r = 0; r < 4; r++) v[r] = acc[r] + boff[m + r];
      *(f32x4*)(off_t + (size_t)pix * 64 + m) = v;
    } else if (f == 5) {
      f32x4 v;
#pragma unroll
      for (int r = 0; r < 4; r++) v[r] = acc[r] + bk[mq + r];
      *(f32x4*)(k_t + (size_t)pix * 16 + mq) = v;
    } else {
      int m = (f - 6) * 16 + mq;
      s4v o;
#pragma unroll
      for (int r = 0; r < 4; r++) o[r] = (short)f2bf(acc[r] + bv[m + r]);
      *(s4v*)(v_t + (size_t)pix * 128 + m) = o;
    }
  }
}

// ---------------------------------------------------------------------------
// K2: fused deformable attention + final GEMM (+BN+ReLU). Unchanged (round 8).
// 512 blocks x 1024 thr; wave w owns query pix0+w; tap-parallel V-gather.
// ---------------------------------------------------------------------------
__global__ __launch_bounds__(1024, 2) void k2_fused(
    const float* __restrict__ q_t, const float* __restrict__ k_t,
    const short* __restrict__ v_t, const float* __restrict__ off_t,
    const short* __restrict__ xh, const short* __restrict__ wb,
    const float* __restrict__ gamma, const float* __restrict__ beta,
    const float* __restrict__ rmean, const float* __restrict__ rvar,
    float* __restrict__ out) {
  __shared__ float s_w[16][32][4];   // 8 KB
  __shared__ int   s_i[16][32][4];   // 8 KB
  __shared__ short attn_s[16 * 136]; // 4.25 KB
  const int tid = threadIdx.x;
  const int wave = tid >> 6, lane = tid & 63;
  const int pix0 = blockIdx.x * 16;

  // ---- phase T: attention, ONE query per wave ----
  {
    const int qidx = pix0 + wave;
    const int b = qidx >> 12;
    const int n = qidx & (NL - 1);
    const int qy = n >> 6, qx = n & 63;

    const float* qp = q_t + (size_t)qidx * 16;
    float qreg[16];
#pragma unroll
    for (int i = 0; i < 16; i += 4) {
      float4 t = *(const float4*)(qp + i);
      qreg[i] = t.x; qreg[i + 1] = t.y; qreg[i + 2] = t.z; qreg[i + 3] = t.w;
    }

    const int pt = lane >> 1, h = lane & 1;
    float2 dxy = *(const float2*)(off_t + (size_t)qidx * 64 + 2 * pt);
    float sx = (float)qx + dxy.x;
    float sy = (float)qy + dxy.y;
    float x0f = floorf(sx), y0f = floorf(sy);
    float wx = sx - x0f, wy = sy - y0f;
    int x0i = (int)x0f, y0i = (int)y0f;
    int x0 = min(63, max(0, x0i)), x1 = min(63, max(0, x0i + 1));
    int y0 = min(63, max(0, y0i)), y1 = min(63, max(0, y0i + 1));

    int   yr  = h ? y1 : y0;
    float wyr = h ? wy : (1.f - wy);
    int   pa = yr * 64 + x0, pb = yr * 64 + x1;
    float wa = wyr * (1.f - wx), wb_ = wyr * wx;

    const float* kb = k_t + (size_t)b * NL * 16;
    float da = 0.f, db = 0.f;
    {
      const float* ka = kb + (size_t)pa * 16;
      const float* kc = kb + (size_t)pb * 16;
#pragma unroll
      for (int i = 0; i < 16; i += 4) {
        float4 a4 = *(const float4*)(ka + i);
        float4 c4 = *(const float4*)(kc + i);
        da = fmaf(qreg[i], a4.x, da); da = fmaf(qreg[i + 1], a4.y, da);
        da = fmaf(qreg[i + 2], a4.z, da); da = fmaf(qreg[i + 3], a4.w, da);
        db = fmaf(qreg[i], c4.x, db); db = fmaf(qreg[i + 1], c4.y, db);
        db = fmaf(qreg[i + 2], c4.z, db); db = fmaf(qreg[i + 3], c4.w, db);
      }
    }
    float part = wa * da + wb_ * db;
    part += __shfl_xor(part, 1, 64);
    float logit = part * 0.25f;

    float m = logit;
#pragma unroll
    for (int s = 32; s > 0; s >>= 1) m = fmaxf(m, __shfl_xor(m, s, 64));
    float e = __expf(logit - m);
    float ssum = e;
#pragma unroll
    for (int s = 32; s > 0; s >>= 1) ssum += __shfl_xor(ssum, s, 64);
    float a = e * 2.f / ssum;   // ssum double-counts each point

    // per-wave tables; same-wave LDS RAW is lgkmcnt-ordered -> no barrier
    s_w[wave][pt][2 * h + 0] = a * wa;
    s_w[wave][pt][2 * h + 1] = a * wb_;
    s_i[wave][pt][2 * h + 0] = pa;
    s_i[wave][pt][2 * h + 1] = pb;

    // ---- V-gather: tap-parallel, 8 channels per lane per point ----
    const int t = lane >> 4, chunk = lane & 15;
    const short* vb = v_t + (size_t)b * NL * 128 + chunk * 8;
    float o[8];
#pragma unroll
    for (int j = 0; j < 8; j++) o[j] = 0.f;
#pragma unroll
    for (int pp = 0; pp < 32; pp++) {
      float w_ = s_w[wave][pp][t];
      int  pix = s_i[wave][pp][t];
      uint4 u = *(const uint4*)(vb + (size_t)pix * 128);
      o[0] = fmaf(w_, bfbits2f(u.x & 0xffffu), o[0]);
      o[1] = fmaf(w_, bfbits2f(u.x >> 16),     o[1]);
      o[2] = fmaf(w_, bfbits2f(u.y & 0xffffu), o[2]);
      o[3] = fmaf(w_, bfbits2f(u.y >> 16),     o[3]);
      o[4] = fmaf(w_, bfbits2f(u.z & 0xffffu), o[4]);
      o[5] = fmaf(w_, bfbits2f(u.z >> 16),     o[5]);
      o[6] = fmaf(w_, bfbits2f(u.w & 0xffffu), o[6]);
      o[7] = fmaf(w_, bfbits2f(u.w >> 16),     o[7]);
    }
    // reduce across the 4 tap-groups (lane bits 4,5)
#pragma unroll
    for (int j = 0; j < 8; j++) {
      o[j] += __shfl_xor(o[j], 16, 64);
      o[j] += __shfl_xor(o[j], 32, 64);
    }
    if (t == 0) {
      uint4 pk;
      pk.x = (unsigned)f2bf(o[0]) | ((unsigned)f2bf(o[1]) << 16);
      pk.y = (unsigned)f2bf(o[2]) | ((unsigned)f2bf(o[3]) << 16);
      pk.z = (unsigned)f2bf(o[4]) | ((unsigned)f2bf(o[5]) << 16);
      pk.w = (unsigned)f2bf(o[6]) | ((unsigned)f2bf(o[7]) << 16);
      *(uint4*)(attn_s + wave * 136 + chunk * 8) = pk;
    }
  }
  __syncthreads();

  // ---- phase F: final GEMM, N=16 px, M=256 over 16 waves (1 frag/wave) ----
  {
    const int quad = lane >> 4, id = lane & 15;
    const int m0 = wave * 16;
    const int pix = pix0 + id;

    f32x4 acc = (f32x4){0.f, 0.f, 0.f, 0.f};
    const short* ap = wb + (size_t)(m0 + id) * 384 + quad * 8;
    const short* bs = attn_s + id * 136 + quad * 8;
    const short* bg = xh + (size_t)pix * 256 + quad * 8;
#pragma unroll
    for (int k = 0; k < 4; k++)
      acc = __builtin_amdgcn_mfma_f32_16x16x32_bf16(
          *(const s8v*)(ap + k * 32), *(const s8v*)(bs + k * 32), acc, 0, 0, 0);
#pragma unroll
    for (int k = 0; k < 8; k++)
      acc = __builtin_amdgcn_mfma_f32_16x16x32_bf16(
          *(const s8v*)(ap + 128 + k * 32), *(const s8v*)(bg + k * 32), acc, 0, 0, 0);

    const int bb = pix >> 12, nlow = pix & (NL - 1);
    const int mbase = m0 + quad * 4;
#pragma unroll
    for (int r = 0; r < 4; r++) {
      int o = mbase + r;
      float s  = gamma[o] * rsqrtf(rvar[o] + 1e-5f);
      float sh = beta[o] - rmean[o] * s;
      out[((size_t)bb * 256 + o) * NL + nlow] = fmaxf(fmaf(acc[r], s, sh), 0.f);
    }
  }
}

// ---------------------------------------------------------------------------
extern "C" void kernel_launch(void* const* d_in, const int* in_sizes, int n_in,
                              void* d_out, int out_size, void* d_ws, size_t ws_size,
                              hipStream_t stream) {
  const float* low   = (const float*)d_in[0];
  const float* high  = (const float*)d_in[1];
  const float* W1    = (const float*)d_in[2];
  const float* b1    = (const float*)d_in[3];
  const float* W2    = (const float*)d_in[4];
  const float* b2    = (const float*)d_in[5];
  const float* Wq    = (const float*)d_in[6];
  const float* bq    = (const float*)d_in[7];
  const float* Wk    = (const float*)d_in[8];
  const float* bk    = (const float*)d_in[9];
  const float* Wv    = (const float*)d_in[10];
  const float* bv    = (const float*)d_in[11];
  const float* Woff  = (const float*)d_in[12];
  const float* boff  = (const float*)d_in[13];
  const float* Wb    = (const float*)d_in[14];
  const float* gamma = (const float*)d_in[15];
  const float* beta  = (const float*)d_in[16];
  const float* rmean = (const float*)d_in[17];
  const float* rvar  = (const float*)d_in[18];
  float* out = (float*)d_out;

  short* ws    = (short*)d_ws;
  short* xh    = ws;                    // [8192][256] bf16 = 2,097,152 sh
  short* v_t   = xh + 2097152;          // [8192][128] bf16
  short* wc    = v_t + 1048576;         // 225,280 bf16
  float* q_t   = (float*)(wc + 225280); // [8192][16] f32
  float* k_t   = q_t + 131072;          // [8192][16] f32
  float* off_t = k_t + 131072;          // [8192][64] f32

  convert_weights_k<<<880, 256, 0, stream>>>(W1, W2, Wq, Woff, Wk, Wv, Wb, wc);
  k1_fused<<<512, 256, 0, stream>>>(low, high, wc, b1, b2, bq, boff, bk, bv,
                                    xh, q_t, k_t, off_t, v_t);
  k2_fused<<<512, 1024, 0, stream>>>(q_t, k_t, v_t, off_t, xh, wc + 126976,
                                     gamma, beta, rmean, rvar, out);
}

// Round 12
// 156.383 us; speedup vs baseline: 1.0507x; 1.0062x over previous
//
#include <hip/hip_runtime.h>
#include <hip/hip_bf16.h>

#define NL 4096   // 64*64 low-res pixels
#define HH 32
#define WH 32

typedef __attribute__((ext_vector_type(8))) short s8v;   // 8 bf16 MFMA A/B frag
typedef __attribute__((ext_vector_type(4))) short s4v;   // 4 bf16 (8B)
typedef __attribute__((ext_vector_type(4))) float f32x4; // MFMA C/D frag

static __device__ inline unsigned short f2bf(float x) {
  __hip_bfloat16 h = __float2bfloat16(x);   // RNE
  return *reinterpret_cast<unsigned short*>(&h);
}
static __device__ inline float bfbits2f(unsigned int lo16) {
  unsigned int u = lo16 << 16;
  return *reinterpret_cast<float*>(&u);
}

// ---------------------------------------------------------------------------
// Weight fp32 -> bf16, packed:
//   [0,65536)        W1   [128][512]
//   [65536,98304)    W2   [128][256]
//   [98304,100352)   Wq   [16][128]   \
//   [100352,108544)  Woff [64][128]    | stage-B concat: 224 rows, K=128
//   [108544,110592)  Wk   [16][128]    |
//   [110592,126976)  Wv   [128][128]  /
//   [126976,225280)  Wb   [256][384]
// ---------------------------------------------------------------------------
__global__ __launch_bounds__(256) void convert_weights_k(
    const float* __restrict__ w1, const float* __restrict__ w2,
    const float* __restrict__ wq, const float* __restrict__ woff,
    const float* __restrict__ wk, const float* __restrict__ wv,
    const float* __restrict__ wb, short* __restrict__ dst) {
  int i = blockIdx.x * 256 + threadIdx.x;
  const float* src; int off;
  if      (i <  65536) { src = w1;   off = 0; }
  else if (i <  98304) { src = w2;   off = 65536; }
  else if (i < 100352) { src = wq;   off = 98304; }
  else if (i < 108544) { src = woff; off = 100352; }
  else if (i < 110592) { src = wk;   off = 108544; }
  else if (i < 126976) { src = wv;   off = 110592; }
  else if (i < 225280) { src = wb;   off = 126976; }
  else return;
  dst[i] = (short)f2bf(src[i - off]);
}

// ---------------------------------------------------------------------------
// K1: fused prep + stageA + stageB (round-6/8 structure — measured best).
// 512 blocks x 256 thr; block handles 16 pixels end-to-end.
// ---------------------------------------------------------------------------
__global__ __launch_bounds__(256) void k1_fused(
    const float* __restrict__ low, const float* __restrict__ high,
    const short* __restrict__ wc,
    const float* __restrict__ b1, const float* __restrict__ b2,
    const float* __restrict__ bq, const float* __restrict__ boff,
    const float* __restrict__ bk, const float* __restrict__ bv,
    short* __restrict__ xh, float* __restrict__ q_t, float* __restrict__ k_t,
    float* __restrict__ off_t, short* __restrict__ v_t) {
  __shared__ short xin_s[16 * 520];
  __shared__ short qf_s[16 * 136];
  __shared__ short vf_s[16 * 136];
  const int tid = threadIdx.x;
  const int pix0 = blockIdx.x * 16;
  const int b = pix0 >> 12;
  const int n0 = pix0 & (NL - 1);

  // ---- phase P: build xin tile ----
  {
    const int nl = tid & 15, cg = tid >> 4;
    const int n = n0 + nl;
    const int y = n >> 6, x = n & 63;
    float sx = x * 0.5f - 0.25f;
    float sy = y * 0.5f - 0.25f;
    float x0f = floorf(sx), y0f = floorf(sy);
    float wx = sx - x0f, wy = sy - y0f;
    int x0i = (int)x0f, y0i = (int)y0f;
    int x0c = min(WH - 1, max(0, x0i)), x1c = min(WH - 1, max(0, x0i + 1));
    int y0c = min(HH - 1, max(0, y0i)), y1c = min(HH - 1, max(0, y0i + 1));
    float w00 = (1.f - wy) * (1.f - wx), w01 = (1.f - wy) * wx;
    float w10 = wy * (1.f - wx),         w11 = wy * wx;
#pragma unroll
    for (int i = 0; i < 16; i++) {
      int c = cg * 16 + i;
      const float* f = high + (size_t)(b * 256 + c) * (HH * WH);
      float v = w00 * f[y0c * WH + x0c] + w01 * f[y0c * WH + x1c]
              + w10 * f[y1c * WH + x0c] + w11 * f[y1c * WH + x1c];
      xin_s[nl * 520 + c] = (short)f2bf(v);
      xin_s[nl * 520 + 256 + c] =
          (short)f2bf(low[(size_t)(b * 256 + c) * NL + n]);
    }
  }
  __syncthreads();

  // ---- store xh (high half of xin, needed by K2 final GEMM) ----
  {
    const int r = tid >> 4, c0 = (tid & 15) * 16;
    s8v v0 = *(const s8v*)(xin_s + r * 520 + c0);
    s8v v1 = *(const s8v*)(xin_s + r * 520 + c0 + 8);
    *(s8v*)(xh + (size_t)(pix0 + r) * 256 + c0) = v0;
    *(s8v*)(xh + (size_t)(pix0 + r) * 256 + c0 + 8) = v1;
  }

  const int wave = tid >> 6, lane = tid & 63;
  const int quad = lane >> 4, id = lane & 15;

  // ---- phase A1: qf = W1 @ xin, M=128 K=512 (2 frags/wave) ----
  {
    f32x4 acc0 = (f32x4){0.f, 0.f, 0.f, 0.f};
    f32x4 acc1 = (f32x4){0.f, 0.f, 0.f, 0.f};
    const short* a0 = wc + (size_t)(wave * 32 + id) * 512 + quad * 8;
    const short* a1 = a0 + 16 * 512;
    const short* bp = xin_s + id * 520 + quad * 8;
#pragma unroll
    for (int kk = 0; kk < 512; kk += 32) {
      s8v bf = *(const s8v*)(bp + kk);
      acc0 = __builtin_amdgcn_mfma_f32_16x16x32_bf16(*(const s8v*)(a0 + kk), bf, acc0, 0, 0, 0);
      acc1 = __builtin_amdgcn_mfma_f32_16x16x32_bf16(*(const s8v*)(a1 + kk), bf, acc1, 0, 0, 0);
    }
    int m0 = wave * 32 + quad * 4;
    s4v o0, o1;
#pragma unroll
    for (int r = 0; r < 4; r++) {
      o0[r] = (short)f2bf(acc0[r] + b1[m0 + r]);
      o1[r] = (short)f2bf(acc1[r] + b1[m0 + 16 + r]);
    }
    *(s4v*)(qf_s + id * 136 + m0) = o0;
    *(s4v*)(qf_s + id * 136 + m0 + 16) = o1;
  }

  // ---- phase A2: vf = W2 @ xin[:,0:256], M=128 K=256 ----
  {
    f32x4 acc0 = (f32x4){0.f, 0.f, 0.f, 0.f};
    f32x4 acc1 = (f32x4){0.f, 0.f, 0.f, 0.f};
    const short* a0 = wc + 65536 + (size_t)(wave * 32 + id) * 256 + quad * 8;
    const short* a1 = a0 + 16 * 256;
    const short* bp = xin_s + id * 520 + quad * 8;
#pragma unroll
    for (int kk = 0; kk < 256; kk += 32) {
      s8v bf = *(const s8v*)(bp + kk);
      acc0 = __builtin_amdgcn_mfma_f32_16x16x32_bf16(*(const s8v*)(a0 + kk), bf, acc0, 0, 0, 0);
      acc1 = __builtin_amdgcn_mfma_f32_16x16x32_bf16(*(const s8v*)(a1 + kk), bf, acc1, 0, 0, 0);
    }
    int m0 = wave * 32 + quad * 4;
    s4v o0, o1;
#pragma unroll
    for (int r = 0; r < 4; r++) {
      o0[r] = (short)f2bf(acc0[r] + b2[m0 + r]);
      o1[r] = (short)f2bf(acc1[r] + b2[m0 + 16 + r]);
    }
    *(s4v*)(vf_s + id * 136 + m0) = o0;
    *(s4v*)(vf_s + id * 136 + m0 + 16) = o1;
  }
  __syncthreads();

  // ---- phase B: 14 m-frags (0:q, 1-4:off, 5:k, 6-13:v), K=128 ----
  for (int f = wave; f < 14; f += 4) {
    const short* ap = wc + 98304 + (size_t)(f * 16 + id) * 128 + quad * 8;
    const short* bp = (f < 5 ? qf_s : vf_s) + id * 136 + quad * 8;
    f32x4 acc = (f32x4){0.f, 0.f, 0.f, 0.f};
#pragma unroll
    for (int kk = 0; kk < 128; kk += 32)
      acc = __builtin_amdgcn_mfma_f32_16x16x32_bf16(
          *(const s8v*)(ap + kk), *(const s8v*)(bp + kk), acc, 0, 0, 0);
    const int pix = pix0 + id;
    const int mq = quad * 4;
    if (f == 0) {
      f32x4 v;
#pragma unroll
      for (int r = 0; r < 4; r++) v[r] = acc[r] + bq[mq + r];
      *(f32x4*)(q_t + (size_t)pix * 16 + mq) = v;
    } else if (f < 5) {
      int m = (f - 1) * 16 + mq;
      f32x4 v;
#pragma unroll
      for (int r = 0; r < 4; r++) v[r] = acc[r] + boff[m + r];
      *(f32x4*)(off_t + (size_t)pix * 64 + m) = v;
    } else if (f == 5) {
      f32x4 v;
#pragma unroll
      for (int r = 0; r < 4; r++) v[r] = acc[r] + bk[mq + r];
      *(f32x4*)(k_t + (size_t)pix * 16 + mq) = v;
    } else {
      int m = (f - 6) * 16 + mq;
      s4v o;
#pragma unroll
      for (int r = 0; r < 4; r++) o[r] = (short)f2bf(acc[r] + bv[m + r]);
      *(s4v*)(v_t + (size_t)pix * 128 + m) = o;
    }
  }
}

// ---------------------------------------------------------------------------
// K2: fused deformable attention + final GEMM (+BN+ReLU). Round-8 winner.
// 512 blocks x 1024 thr; wave w owns query pix0+w; tap-parallel V-gather.
// ---------------------------------------------------------------------------
__global__ __launch_bounds__(1024, 2) void k2_fused(
    const float* __restrict__ q_t, const float* __restrict__ k_t,
    const short* __restrict__ v_t, const float* __restrict__ off_t,
    const short* __restrict__ xh, const short* __restrict__ wb,
    const float* __restrict__ gamma, const float* __restrict__ beta,
    const float* __restrict__ rmean, const float* __restrict__ rvar,
    float* __restrict__ out) {
  __shared__ float s_w[16][32][4];   // 8 KB
  __shared__ int   s_i[16][32][4];   // 8 KB
  __shared__ short attn_s[16 * 136]; // 4.25 KB
  const int tid = threadIdx.x;
  const int wave = tid >> 6, lane = tid & 63;
  const int pix0 = blockIdx.x * 16;

  // ---- phase T: attention, ONE query per wave ----
  {
    const int qidx = pix0 + wave;
    const int b = qidx >> 12;
    const int n = qidx & (NL - 1);
    const int qy = n >> 6, qx = n & 63;

    const float* qp = q_t + (size_t)qidx * 16;
    float qreg[16];
#pragma unroll
    for (int i = 0; i < 16; i += 4) {
      float4 t = *(const float4*)(qp + i);
      qreg[i] = t.x; qreg[i + 1] = t.y; qreg[i + 2] = t.z; qreg[i + 3] = t.w;
    }

    const int pt = lane >> 1, h = lane & 1;
    float2 dxy = *(const float2*)(off_t + (size_t)qidx * 64 + 2 * pt);
    float sx = (float)qx + dxy.x;
    float sy = (float)qy + dxy.y;
    float x0f = floorf(sx), y0f = floorf(sy);
    float wx = sx - x0f, wy = sy - y0f;
    int x0i = (int)x0f, y0i = (int)y0f;
    int x0 = min(63, max(0, x0i)), x1 = min(63, max(0, x0i + 1));
    int y0 = min(63, max(0, y0i)), y1 = min(63, max(0, y0i + 1));

    int   yr  = h ? y1 : y0;
    float wyr = h ? wy : (1.f - wy);
    int   pa = yr * 64 + x0, pb = yr * 64 + x1;
    float wa = wyr * (1.f - wx), wb_ = wyr * wx;

    const float* kb = k_t + (size_t)b * NL * 16;
    float da = 0.f, db = 0.f;
    {
      const float* ka = kb + (size_t)pa * 16;
      const float* kc = kb + (size_t)pb * 16;
#pragma unroll
      for (int i = 0; i < 16; i += 4) {
        float4 a4 = *(const float4*)(ka + i);
        float4 c4 = *(const float4*)(kc + i);
        da = fmaf(qreg[i], a4.x, da); da = fmaf(qreg[i + 1], a4.y, da);
        da = fmaf(qreg[i + 2], a4.z, da); da = fmaf(qreg[i + 3], a4.w, da);
        db = fmaf(qreg[i], c4.x, db); db = fmaf(qreg[i + 1], c4.y, db);
        db = fmaf(qreg[i + 2], c4.z, db); db = fmaf(qreg[i + 3], c4.w, db);
      }
    }
    float part = wa * da + wb_ * db;
    part += __shfl_xor(part, 1, 64);
    float logit = part * 0.25f;

    float m = logit;
#pragma unroll
    for (int s = 32; s > 0; s >>= 1) m = fmaxf(m, __shfl_xor(m, s, 64));
    float e = __expf(logit - m);
    float ssum = e;
#pragma unroll
    for (int s = 32; s > 0; s >>= 1) ssum += __shfl_xor(ssum, s, 64);
    float a = e * 2.f / ssum;   // ssum double-counts each point

    // per-wave tables; same-wave LDS RAW is lgkmcnt-ordered -> no barrier
    s_w[wave][pt][2 * h + 0] = a * wa;
    s_w[wave][pt][2 * h + 1] = a * wb_;
    s_i[wave][pt][2 * h + 0] = pa;
    s_i[wave][pt][2 * h + 1] = pb;

    // ---- V-gather: tap-parallel, 8 channels per lane per point ----
    const int t = lane >> 4, chunk = lane & 15;
    const short* vb = v_t + (size_t)b * NL * 128 + chunk * 8;
    float o[8];
#pragma unroll
    for (int j = 0; j < 8; j++) o[j] = 0.f;
#pragma unroll
    for (int pp = 0; pp < 32; pp++) {
      float w_ = s_w[wave][pp][t];
      int  pix = s_i[wave][pp][t];
      uint4 u = *(const uint4*)(vb + (size_t)pix * 128);
      o[0] = fmaf(w_, bfbits2f(u.x & 0xffffu), o[0]);
      o[1] = fmaf(w_, bfbits2f(u.x >> 16),     o[1]);
      o[2] = fmaf(w_, bfbits2f(u.y & 0xffffu), o[2]);
      o[3] = fmaf(w_, bfbits2f(u.y >> 16),     o[3]);
      o[4] = fmaf(w_, bfbits2f(u.z & 0xffffu), o[4]);
      o[5] = fmaf(w_, bfbits2f(u.z >> 16),     o[5]);
      o[6] = fmaf(w_, bfbits2f(u.w & 0xffffu), o[6]);
      o[7] = fmaf(w_, bfbits2f(u.w >> 16),     o[7]);
    }
    // reduce across the 4 tap-groups (lane bits 4,5)
#pragma unroll
    for (int j = 0; j < 8; j++) {
      o[j] += __shfl_xor(o[j], 16, 64);
      o[j] += __shfl_xor(o[j], 32, 64);
    }
    if (t == 0) {
      uint4 pk;
      pk.x = (unsigned)f2bf(o[0]) | ((unsigned)f2bf(o[1]) << 16);
      pk.y = (unsigned)f2bf(o[2]) | ((unsigned)f2bf(o[3]) << 16);
      pk.z = (unsigned)f2bf(o[4]) | ((unsigned)f2bf(o[5]) << 16);
      pk.w = (unsigned)f2bf(o[6]) | ((unsigned)f2bf(o[7]) << 16);
      *(uint4*)(attn_s + wave * 136 + chunk * 8) = pk;
    }
  }
  __syncthreads();

  // ---- phase F: final GEMM, N=16 px, M=256 over 16 waves (1 frag/wave) ----
  {
    const int quad = lane >> 4, id = lane & 15;
    const int m0 = wave * 16;
    const int pix = pix0 + id;

    f32x4 acc = (f32x4){0.f, 0.f, 0.f, 0.f};
    const short* ap = wb + (size_t)(m0 + id) * 384 + quad * 8;
    const short* bs = attn_s + id * 136 + quad * 8;
    const short* bg = xh + (size_t)pix * 256 + quad * 8;
#pragma unroll
    for (int k = 0; k < 4; k++)
      acc = __builtin_amdgcn_mfma_f32_16x16x32_bf16(
          *(const s8v*)(ap + k * 32), *(const s8v*)(bs + k * 32), acc, 0, 0, 0);
#pragma unroll
    for (int k = 0; k < 8; k++)
      acc = __builtin_amdgcn_mfma_f32_16x16x32_bf16(
          *(const s8v*)(ap + 128 + k * 32), *(const s8v*)(bg + k * 32), acc, 0, 0, 0);

    const int bb = pix >> 12, nlow = pix & (NL - 1);
    const int mbase = m0 + quad * 4;
#pragma unroll
    for (int r = 0; r < 4; r++) {
      int o = mbase + r;
      float s  = gamma[o] * rsqrtf(rvar[o] + 1e-5f);
      float sh = beta[o] - rmean[o] * s;
      out[((size_t)bb * 256 + o) * NL + nlow] = fmaxf(fmaf(acc[r], s, sh), 0.f);
    }
  }
}

// ---------------------------------------------------------------------------
extern "C" void kernel_launch(void* const* d_in, const int* in_sizes, int n_in,
                              void* d_out, int out_size, void* d_ws, size_t ws_size,
                              hipStream_t stream) {
  const float* low   = (const float*)d_in[0];
  const float* high  = (const float*)d_in[1];
  const float* W1    = (const float*)d_in[2];
  const float* b1    = (const float*)d_in[3];
  const float* W2    = (const float*)d_in[4];
  const float* b2    = (const float*)d_in[5];
  const float* Wq    = (const float*)d_in[6];
  const float* bq    = (const float*)d_in[7];
  const float* Wk    = (const float*)d_in[8];
  const float* bk    = (const float*)d_in[9];
  const float* Wv    = (const float*)d_in[10];
  const float* bv    = (const float*)d_in[11];
  const float* Woff  = (const float*)d_in[12];
  const float* boff  = (const float*)d_in[13];
  const float* Wb    = (const float*)d_in[14];
  const float* gamma = (const float*)d_in[15];
  const float* beta  = (const float*)d_in[16];
  const float* rmean = (const float*)d_in[17];
  const float* rvar  = (const float*)d_in[18];
  float* out = (float*)d_out;

  short* ws    = (short*)d_ws;
  short* xh    = ws;                    // [8192][256] bf16 = 2,097,152 sh
  short* v_t   = xh + 2097152;          // [8192][128] bf16
  short* wc    = v_t + 1048576;         // 225,280 bf16
  float* q_t   = (float*)(wc + 225280); // [8192][16] f32
  float* k_t   = q_t + 131072;          // [8192][16] f32
  float* off_t = k_t + 131072;          // [8192][64] f32

  convert_weights_k<<<880, 256, 0, stream>>>(W1, W2, Wq, Woff, Wk, Wv, Wb, wc);
  k1_fused<<<512, 256, 0, stream>>>(low, high, wc, b1, b2, bq, boff, bk, bv,
                                    xh, q_t, k_t, off_t, v_t);
  k2_fused<<<512, 1024, 0, stream>>>(q_t, k_t, v_t, off_t, xh, wc + 126976,
                                     gamma, beta, rmean, rvar, out);
}